// Round 5
// baseline (67022.864 us; speedup 1.0000x reference)
//
#include <hip/hip_runtime.h>
#include <cstdint>
#include <cstddef>

#define NWG 64
#define NTHR 1024
#define TSTEPS 16384
#define HDIM 1024
#define EDIM 13
#define HLDIM 512

typedef unsigned long long ull;

// ---------------------------------------------------------------------------
// Init kernel: re-arm the tagged h-record ring and u-record every call (d_ws
// is poisoned once with 0xAA and never re-poisoned between graph replays; a
// finished replay also leaves end-state tags behind, so every tag word must
// be rewritten each launch).
// hrec[parity][i] = { low32: f32 h value, high32: u32 step tag }, 4 parities.
// ---------------------------------------------------------------------------
__global__ void k_init(const float* __restrict__ h0, ull* __restrict__ hrec,
                       ull* __restrict__ urec) {
  int i = threadIdx.x;  // 1024 threads
  hrec[i] = (ull)__float_as_uint(h0[i]);  // {h0, tag=0}
  hrec[HDIM + i] = 0ull;
  hrec[2 * HDIM + i] = 0ull;
  hrec[3 * HDIM + i] = 0ull;
  if (i < HLDIM) urec[i] = 0ull;
}

// ---------------------------------------------------------------------------
// Persistent LSTM kernel. 64 WGs x 1024 threads (16 waves), one WG per CU.
// WG w owns hidden units [16w,16w+16); wave k owns unit 16w+k (its 4 gate
// rows live in the wave's four 16-lane groups). W_hh: 64 floats/thread in
// VGPRs.
// Rounds 3/4 failure: 512-thr WGs let the allocator target >1 WG/CU with a
// ~96-VGPR budget -> wreg spilled to scratch (VGPR_Count 88/92). Fix is
// structural: 16-wave WG + static LDS > 80 KB means only ONE WG fits a CU,
// so the only legal occupancy is 4 waves/SIMD -> 128-VGPR budget, and the
// 64-float W chunk (+~35 working) fits with headroom. waves_per_eu(4,4)
// declares the same thing explicitly.
// Cross-WG sync: self-validating {value, tag} 8-byte records in a 4-deep
// parity ring, relaxed agent-scope 64-bit atomics (single-copy atomic,
// serviced at the device coherent point -> immune to non-coherent per-XCD
// L2s). One coherent round trip + one __syncthreads per step; each thread
// polls exactly ONE record.
// ---------------------------------------------------------------------------
__global__ __launch_bounds__(NTHR)
__attribute__((amdgpu_waves_per_eu(4, 4))) void k_main(
    const float* __restrict__ x, const float* __restrict__ c0,
    const float* __restrict__ Wih, const float* __restrict__ Whh,
    const float* __restrict__ bih, const float* __restrict__ bhh,
    const float* __restrict__ W1, const float* __restrict__ b1,
    const float* __restrict__ W2, const float* __restrict__ b2,
    float* __restrict__ out, ull* hrec, ull* urec, int never) {
  const int w = blockIdx.x;
  const int tid = threadIdx.x;
  const int sub = tid & 15;   // col-chunk index within row (16 x 64 cols)
  const int row = tid >> 4;   // local gate row 0..63
  const int wave = tid >> 6;  // 0..15 == local unit
  const int lane = tid & 63;
  const int g = row & 3;                    // 0=i 1=f 2=g 3=o
  const int grow = g * HDIM + w * 16 + (row >> 2);  // global gate row

  __shared__ float4 lds_h4[2][HDIM / 4];  // double-buffered by step parity
  __shared__ float lds_x[2][16];
  __shared__ float lds_wih[64][17];  // stride 17: conflict-free reads
  __shared__ float lds_bsum[64];
  __shared__ float lds_r0[8], lds_r1[8];
  // Occupancy clamp: push static LDS past 80 KB so a second 16-wave WG can
  // never co-reside -> register allocator must budget 128 VGPRs/thread.
  __shared__ float lds_pad[17408];  // 68 KB
  float* lds_hf = (float*)lds_h4;   // [2][1024] flat
  if (never) ((volatile float*)lds_pad)[0] = 1.f;  // keep pad allocated

  // ---- load this thread's W_hh chunk (16 float4s = 64 cols), rotated so
  // the 16 distinct LDS b128 addresses per 16-lane group spread 2-per-bank-
  // group at compute time (2-way aliasing = free on CDNA4).
  float4 wreg[16];
  const float4* wrow4 = (const float4*)(Whh + (size_t)grow * HDIM);
#pragma unroll
  for (int i = 0; i < 16; ++i) wreg[i] = wrow4[sub * 16 + ((i + sub) & 15)];
  // Pin: asm claims to rewrite each value -> no rematerialization from
  // global inside the loop.
#pragma unroll
  for (int i = 0; i < 16; ++i)
    asm volatile("" : "+v"(wreg[i].x), "+v"(wreg[i].y), "+v"(wreg[i].z),
                     "+v"(wreg[i].w));

  if (tid < 64) {
    int g2 = tid & 3, lu2 = tid >> 2;
    int gr2 = g2 * HDIM + w * 16 + lu2;
#pragma unroll
    for (int e = 0; e < EDIM; ++e) lds_wih[tid][e] = Wih[gr2 * EDIM + e];
    lds_bsum[tid] = bih[gr2] + bhh[gr2];
  }
  // cell state: lane 0 of wave k owns unit 16w+k
  float cst = c0[w * 16 + wave];
  __syncthreads();

  const float gsc = (g == 2) ? 2.f : 1.f;  // tanh via 2*sigmoid(2x)-1

  for (int t = 1; t <= TSTEPS; ++t) {
    const int lp = (t - 1) & 1;  // LDS parity (2-deep, barrier-separated)
    // ---- x_t prefetch: issue before the poll so its latency hides there
    float xv = 0.f;
    if (tid < EDIM) xv = x[(size_t)(t - 1) * EDIM + tid];

    // ---- poll this thread's ONE {h, tag} record of h_{t-1}; the poll load
    // IS the data load (one coherent round trip). 4-deep ring: overwrite of
    // a tag-t record (by tag t+4) needs three cross-WG dependence chains of
    // separation -> overwrite-before-read unreachable.
    const ull* rec = hrec + (size_t)((t - 1) & 3) * HDIM + tid;
    const unsigned want = (unsigned)(t - 1);
    ull v = __hip_atomic_load(rec, __ATOMIC_RELAXED, __HIP_MEMORY_SCOPE_AGENT);
    while ((unsigned)(v >> 32) != want)
      v = __hip_atomic_load(rec, __ATOMIC_RELAXED, __HIP_MEMORY_SCOPE_AGENT);
    lds_hf[lp * HDIM + tid] = __uint_as_float((unsigned)v);
    if (tid < EDIM) lds_x[lp][tid] = xv;
    __syncthreads();

    // ---- gate pre-activation; 4-way split accumulator (short dep chains)
    float acc0 = 0.f, acc1 = 0.f, acc2 = 0.f, acc3 = 0.f;
    if (sub < EDIM) acc0 = lds_wih[row][sub] * lds_x[lp][sub];
    if (sub == 0) acc1 = lds_bsum[row];
#pragma unroll
    for (int i = 0; i < 16; ++i) {
      float4 hv = lds_h4[lp][sub * 16 + ((i + sub) & 15)];
      float4 wv = wreg[i];
      float pr = wv.x * hv.x + wv.y * hv.y;
      float ps = wv.z * hv.z + wv.w * hv.w;
      if ((i & 3) == 0) { acc0 += pr; acc1 += ps; }
      else if ((i & 3) == 1) { acc2 += pr; acc3 += ps; }
      else if ((i & 3) == 2) { acc0 += pr; acc1 += ps; }
      else { acc2 += pr; acc3 += ps; }
    }
    float acc = (acc0 + acc1) + (acc2 + acc3);
    acc += __shfl_xor(acc, 1);
    acc += __shfl_xor(acc, 2);
    acc += __shfl_xor(acc, 4);
    acc += __shfl_xor(acc, 8);

    // ---- activations in parallel on all lanes (one exp chain each)
    float e = __expf(-gsc * acc);
    float y = 1.f / (1.f + e);
    float act = (g == 2) ? 2.f * y - 1.f : y;

    // gate rows of this wave's unit live at lanes 0,16,32,48
    float ai = __shfl(act, 0);
    float af = __shfl(act, 16);
    float ag = __shfl(act, 32);
    float ao = __shfl(act, 48);
    if (lane == 0) {
      cst = af * cst + ai * ag;
      float e2 = __expf(-2.f * cst);
      float hn = ao * (2.f / (1.f + e2) - 1.f);
      ull pk = ((ull)(unsigned)t << 32) | (ull)__float_as_uint(hn);
      __hip_atomic_store(&hrec[(size_t)(t & 3) * HDIM + w * 16 + wave], pk,
                         __ATOMIC_RELAXED, __HIP_MEMORY_SCOPE_AGENT);
    }
    // no end-of-step barrier: publish is self-validating; LDS buffer reuse
    // is two steps away and ordered by the intervening step's barrier.
  }

  // ---- tail step 1: u = tanh(W1 @ h_T + b1), 8 rows per WG --------------
  {
    // h_T: tag TSTEPS lives in ring parity (TSTEPS & 3) == 0
    const unsigned want = (unsigned)TSTEPS;
    const ull* rec = hrec + tid;
    ull v = __hip_atomic_load(rec, __ATOMIC_RELAXED, __HIP_MEMORY_SCOPE_AGENT);
    while ((unsigned)(v >> 32) != want)
      v = __hip_atomic_load(rec, __ATOMIC_RELAXED, __HIP_MEMORY_SCOPE_AGENT);
    lds_hf[tid] = __uint_as_float((unsigned)v);
  }
  __syncthreads();
  if (wave < 8) {
    int r1 = 8 * w + wave;  // one MLP row per wave
    const float* w1p = W1 + (size_t)r1 * HDIM + lane * 16;
    float a0 = 0.f, a1 = 0.f;
#pragma unroll
    for (int i = 0; i < 16; i += 2) {
      a0 += w1p[i] * lds_hf[lane * 16 + i];
      a1 += w1p[i + 1] * lds_hf[lane * 16 + i + 1];
    }
    float acc1 = a0 + a1;
#pragma unroll
    for (int m = 1; m < 64; m <<= 1) acc1 += __shfl_xor(acc1, m);
    if (lane == 0) {
      float e2 = __expf(-2.f * (acc1 + b1[r1]));
      float u = 2.f / (1.f + e2) - 1.f;
      ull pk = (1ull << 32) | (ull)__float_as_uint(u);
      __hip_atomic_store(&urec[r1], pk, __ATOMIC_RELAXED,
                         __HIP_MEMORY_SCOPE_AGENT);
    }
  }

  // ---- tail step 2: out = W2 @ u + b2, WG 0 only -------------------------
  if (w == 0) {
    float p0 = 0.f, p1 = 0.f;
    if (tid < HLDIM) {
      ull uv = __hip_atomic_load(&urec[tid], __ATOMIC_RELAXED,
                                 __HIP_MEMORY_SCOPE_AGENT);
      while ((unsigned)(uv >> 32) != 1u)
        uv = __hip_atomic_load(&urec[tid], __ATOMIC_RELAXED,
                               __HIP_MEMORY_SCOPE_AGENT);
      float u = __uint_as_float((unsigned)uv);
      p0 = W2[tid] * u;
      p1 = W2[HLDIM + tid] * u;
    }
#pragma unroll
    for (int m = 1; m < 64; m <<= 1) {
      p0 += __shfl_xor(p0, m);
      p1 += __shfl_xor(p1, m);
    }
    if (lane == 0 && wave < 8) {
      lds_r0[wave] = p0;
      lds_r1[wave] = p1;
    }
    __syncthreads();
    if (tid == 0) {
      float o0 = b2[0], o1 = b2[1];
#pragma unroll
      for (int k = 0; k < 8; ++k) {
        o0 += lds_r0[k];
        o1 += lds_r1[k];
      }
      out[0] = o0;
      out[1] = o1;
    }
  }
}

extern "C" void kernel_launch(void* const* d_in, const int* in_sizes, int n_in,
                              void* d_out, int out_size, void* d_ws,
                              size_t ws_size, hipStream_t stream) {
  const float* x = (const float*)d_in[0];
  const float* h0 = (const float*)d_in[1];
  const float* c0 = (const float*)d_in[2];
  const float* Wih = (const float*)d_in[3];
  const float* Whh = (const float*)d_in[4];
  const float* bih = (const float*)d_in[5];
  const float* bhh = (const float*)d_in[6];
  const float* W1 = (const float*)d_in[7];
  const float* b1 = (const float*)d_in[8];
  const float* W2 = (const float*)d_in[9];
  const float* b2 = (const float*)d_in[10];
  float* out = (float*)d_out;

  ull* hrec = (ull*)d_ws;                                    // 4*1024*8 = 32 KB
  ull* urec = (ull*)((char*)d_ws + 4 * HDIM * sizeof(ull));  // 4 KB

  k_init<<<1, NTHR, 0, stream>>>(h0, hrec, urec);
  k_main<<<NWG, NTHR, 0, stream>>>(x, c0, Wih, Whh, bih, bhh, W1, b1, W2, b2,
                                   out, hrec, urec, 0);
}